// Round 13
// baseline (398.449 us; speedup 1.0000x reference)
//
#include <hip/hip_runtime.h>
#include <hip/hip_bf16.h>

typedef __bf16 bf16_t;
typedef unsigned short u16;
typedef short short8 __attribute__((ext_vector_type(8)));
typedef float f32x4 __attribute__((ext_vector_type(4)));

#define BSHIFT 9            // 512 dst-rows per bucket
#define CAP 8192            // fixed slots per bucket (expected 6144 +- 78; 26 sigma)
#define PTILE 2048          // edges per partition tile (256 thr x 8)

__device__ inline short f2bs(float v) {
    bf16_t h = (bf16_t)v;
    return __builtin_bit_cast(short, h);
}
__device__ inline float uif(unsigned u) { return __builtin_bit_cast(float, u); }

// ---------------- mega kernel: partition (role 0, scheduled first) + prep ----------
// Partition and prep are data-independent, so they share ONE launch: partition
// tiles get the low blockIdx range (start first, long pole), convert/weight/
// composite/bias blocks fill the machine behind them. gcursor is ZERO-ORIGIN
// (gbase = b*CAP + fetch_add) so a plain memset replaces the ordered init.
//
// wh mats (transposed [n*64+k], bf16):
//   0..5  Wn[l*3+e]   6,7 WrB[l]   8,9 WrA[l]=Wr[l,1]+Wr[l,2]   10 W_out
//   11 Wn[1,0]@Wout  12 Wr[1,0]@Wout  13 Wn[1,1]@Wout  14 Wn[1,2]@Wout  15 WrA[1]@Wout
// biasC f32[4][64]: 0=b[0,0]; 1=b[0,1]+b[0,2]; 2=b[1,0]@Wout+b_out; 3=(b[1,1]+b[1,2])@Wout+b_out
__global__ __launch_bounds__(256) void mega_prep_partition(
    const float* __restrict__ xA, const float* __restrict__ xB,
    const float* __restrict__ Wn, const float* __restrict__ Wr,
    const float* __restrict__ Wout, const float* __restrict__ b,
    const float* __restrict__ b_out,
    const int* __restrict__ s0, const int* __restrict__ d0,
    const int* __restrict__ s1, const int* __restrict__ d1,
    const int* __restrict__ s2, const int* __restrict__ d2,
    u16* __restrict__ plane0, u16* __restrict__ wh,
    int* __restrict__ gcursor, float* __restrict__ biasC,
    int* __restrict__ pairs,
    int NA, int NB, int E, int total, int ntiles) {
    __shared__ __align__(16) char smem[32768];   // union: partition 8KB / composite 32KB
    int bi = blockIdx.x;
    int tid = threadIdx.x;

    if (bi < ntiles) {
        // ---- partition role: one 2048-edge tile, scan-free, direct scatter ----
        int* hist = (int*)smem;
        int* gbase = hist + 1024;
        for (int i = tid; i < 1024; i += 256) hist[i] = 0;
        __syncthreads();
        int tile = bi * PTILE;
        int mybkt[8], mypk[8], myrank[8];
#pragma unroll
        for (int j = 0; j < 8; j++) {
            int idx = tile + j * 256 + tid;
            int g = -1, s = 0;
            if (idx < total) {
                if (idx < E) { s = s0[idx]; g = d0[idx]; }
                else if (idx < 2 * E) { s = s1[idx - E]; g = NB + d1[idx - E]; }
                else { s = s2[idx - 2 * E]; g = NB + NA + d2[idx - 2 * E]; }
            }
            if (g >= 0) {
                mybkt[j] = g >> BSHIFT;
                mypk[j] = ((g & ((1 << BSHIFT) - 1)) << 17) | s;
                myrank[j] = atomicAdd(&hist[mybkt[j]], 1);
            } else mybkt[j] = -1;
        }
        __syncthreads();
        for (int bq = tid; bq < 1024; bq += 256) {
            int c = hist[bq];
            if (c) gbase[bq] = bq * CAP + atomicAdd(&gcursor[bq], c);
        }
        __syncthreads();
#pragma unroll
        for (int j = 0; j < 8; j++) {
            if (mybkt[j] >= 0)
                pairs[gbase[mybkt[j]] + myrank[j]] = mypk[j];
        }
        return;
    }

    bi -= ntiles;
    int nA4 = NA * 16, nB4 = NB * 16;
    int bA = (nA4 + 255) / 256, bB = (nB4 + 255) / 256;
    if (bi < bA + bB) {
        // ---- convert role: f32 -> bf16 plane ----
        const float* in = (bi < bA) ? xA : xB;
        u16* out = (bi < bA) ? plane0 : plane0 + (size_t)NA * 64;
        int i = (bi < bA ? bi : bi - bA) * 256 + tid;
        int n4 = (bi < bA) ? nA4 : nB4;
        if (i >= n4) return;
        float4 v = ((const float4*)in)[i];
        u16 o[4];
        o[0] = (u16)f2bs(v.x); o[1] = (u16)f2bs(v.y);
        o[2] = (u16)f2bs(v.z); o[3] = (u16)f2bs(v.w);
        *(uint2*)(out + (size_t)i * 4) = *(uint2*)o;
        return;
    }
    if (bi < bA + bB + 11) {
        // ---- weight transpose role ----
        int mat = bi - bA - bB;      // 0..10
        u16* dstp = wh + (size_t)mat * 4096;
        for (int i = tid; i < 4096; i += 256) {
            int k = i >> 6, n = i & 63;
            float v;
            if (mat < 6) v = Wn[(size_t)mat * 4096 + i];
            else if (mat < 8) v = Wr[(size_t)((mat - 6) * 3 + 0) * 4096 + i];
            else if (mat < 10) v = Wr[(size_t)((mat - 8) * 3 + 1) * 4096 + i]
                                 + Wr[(size_t)((mat - 8) * 3 + 2) * 4096 + i];
            else v = Wout[i];
            dstp[n * 64 + k] = (u16)f2bs(v);
        }
        return;
    }
    if (bi < bA + bB + 11 + 5) {
        // ---- composite role: W' = Wsrc @ W_out, LDS-staged (round-9 lesson:
        // scalar-global chains were a 130us latency tail on 5 CUs) ----
        int c = bi - bA - bB - 11;   // 0..4
        const float* Wsrc;
        const float* Wsrc2 = nullptr;
        if (c == 0) Wsrc = Wn + (size_t)3 * 4096;        // Wn[1,0]
        else if (c == 1) Wsrc = Wr + (size_t)3 * 4096;   // Wr[1,0]
        else if (c == 2) Wsrc = Wn + (size_t)4 * 4096;   // Wn[1,1]
        else if (c == 3) Wsrc = Wn + (size_t)5 * 4096;   // Wn[1,2]
        else { Wsrc = Wr + (size_t)4 * 4096; Wsrc2 = Wr + (size_t)5 * 4096; }
        float* Ws = (float*)smem;
        float* Wo = Ws + 4096;
        for (int i = tid; i < 4096; i += 256) {
            float w = Wsrc[i];
            if (Wsrc2) w += Wsrc2[i];
            Ws[i] = w;
            Wo[i] = Wout[i];
        }
        __syncthreads();
        u16* dstp = wh + (size_t)(11 + c) * 4096;
        for (int it = 0; it < 16; ++it) {
            int i = it * 256 + tid;
            int k = i >> 6, n = i & 63;
            float p0 = 0.f, p1 = 0.f, p2 = 0.f, p3 = 0.f;
#pragma unroll
            for (int j = 0; j < 64; j += 4) {
                p0 += Ws[k * 64 + j]     * Wo[j * 64 + n];
                p1 += Ws[k * 64 + j + 1] * Wo[(j + 1) * 64 + n];
                p2 += Ws[k * 64 + j + 2] * Wo[(j + 2) * 64 + n];
                p3 += Ws[k * 64 + j + 3] * Wo[(j + 3) * 64 + n];
            }
            dstp[n * 64 + k] = (u16)f2bs((p0 + p1) + (p2 + p3));
        }
        return;
    }
    // ---- bias role ----
    if (tid < 64) {
        int n = tid;
        float s0v = b_out[n], s1v = b_out[n];
        for (int j = 0; j < 64; j++) {
            float wo = Wout[j * 64 + n];
            s0v += b[3 * 64 + j] * wo;                      // b[1,0]
            s1v += (b[4 * 64 + j] + b[5 * 64 + j]) * wo;    // b[1,1]+b[1,2]
        }
        biasC[0 * 64 + n] = b[0 * 64 + n];
        biasC[1 * 64 + n] = b[1 * 64 + n] + b[2 * 64 + n];
        biasC[2 * 64 + n] = s0v;
        biasC[3 * 64 + n] = s1v;
    }
}

// bucket b: order pairs into colidx segments; emit per-row [off_s, off_e).
// Cursor is zero-origin: p1 = b*CAP + gcursor[b].
__global__ __launch_bounds__(512) void bucket_fill(const int* __restrict__ pairs,
                                                   const int* __restrict__ gcursor,
                                                   int* __restrict__ off_s,
                                                   int* __restrict__ off_e,
                                                   int* __restrict__ colidx, int M) {
    int b = blockIdx.x;
    int gb = b << BSHIFT;
    __shared__ int cnt[512], cur[512], wsum[8];
    int tid = threadIdx.x;
    int lane = tid & 63, w = tid >> 6;
    int p0 = b * CAP, p1 = p0 + gcursor[b];
    cnt[tid] = 0;
    __syncthreads();
    for (int e = p0 + tid; e < p1; e += 512)
        atomicAdd(&cnt[(unsigned)pairs[e] >> 17], 1);
    __syncthreads();
    int v = cnt[tid];
    int x = v;
#pragma unroll
    for (int off = 1; off < 64; off <<= 1) {
        int n = __shfl_up(x, off);
        if (lane >= off) x += n;
    }
    if (lane == 63) wsum[w] = x;
    __syncthreads();
    if (tid == 0) {
        int s = 0;
#pragma unroll
        for (int i = 0; i < 8; i++) { int t = wsum[i]; wsum[i] = s; s += t; }
    }
    __syncthreads();
    int excl = x - v + wsum[w];
    cur[tid] = excl;
    int g = gb + tid;
    if (g < M) { off_s[g] = p0 + excl; off_e[g] = p0 + excl + v; }
    __syncthreads();
    for (int e = p0 + tid; e < p1; e += 512) {
        int p = pairs[e];
        int pos = atomicAdd(&cur[(unsigned)p >> 17], 1);
        colidx[p0 + pos] = p & 0x1FFFF;
    }
}

// ---------------- gather one segment -> packed bf16 x8 (per lane, 1/8 row) ----------
// Same quad-pipelined loop as the proven standalone gather (59us, L2-miss-BW bound).
__device__ __forceinline__ void acc8(uint4 u, f32x4& a0, f32x4& a1) {
    a0[0] += uif(u.x << 16); a0[1] += uif(u.x & 0xFFFF0000u);
    a0[2] += uif(u.y << 16); a0[3] += uif(u.y & 0xFFFF0000u);
    a1[0] += uif(u.z << 16); a1[1] += uif(u.z & 0xFFFF0000u);
    a1[2] += uif(u.w << 16); a1[3] += uif(u.w & 0xFFFF0000u);
}

__device__ __forceinline__ uint4 gather_seg(const char* __restrict__ tab,
                                            const int* __restrict__ colidx,
                                            int s0, int s1, unsigned fo) {
    f32x4 a0 = {0.f, 0.f, 0.f, 0.f}, a1 = {0.f, 0.f, 0.f, 0.f};
    int e = s0;
    if (e + 3 < s1) {
        int c0 = colidx[e], c1 = colidx[e + 1];
        int c2 = colidx[e + 2], c3 = colidx[e + 3];
        while (e + 7 < s1) {
            uint4 u0 = *(const uint4*)(tab + (((unsigned)c0 << 7) | fo));
            uint4 u1 = *(const uint4*)(tab + (((unsigned)c1 << 7) | fo));
            uint4 u2 = *(const uint4*)(tab + (((unsigned)c2 << 7) | fo));
            uint4 u3 = *(const uint4*)(tab + (((unsigned)c3 << 7) | fo));
            c0 = colidx[e + 4]; c1 = colidx[e + 5];
            c2 = colidx[e + 6]; c3 = colidx[e + 7];
            acc8(u0, a0, a1); acc8(u1, a0, a1);
            acc8(u2, a0, a1); acc8(u3, a0, a1);
            e += 4;
        }
        {
            uint4 u0 = *(const uint4*)(tab + (((unsigned)c0 << 7) | fo));
            uint4 u1 = *(const uint4*)(tab + (((unsigned)c1 << 7) | fo));
            uint4 u2 = *(const uint4*)(tab + (((unsigned)c2 << 7) | fo));
            uint4 u3 = *(const uint4*)(tab + (((unsigned)c3 << 7) | fo));
            acc8(u0, a0, a1); acc8(u1, a0, a1);
            acc8(u2, a0, a1); acc8(u3, a0, a1);
            e += 4;
        }
    }
    for (; e < s1; ++e) {
        int c = colidx[e];
        uint4 u = *(const uint4*)(tab + (((unsigned)c << 7) | fo));
        acc8(u, a0, a1);
    }
    float inv = 1.0f / fmaxf((float)(s1 - s0), 1.0f);
    u16 o[8];
#pragma unroll
    for (int i = 0; i < 4; i++) o[i] = (u16)f2bs(a0[i] * inv);
#pragma unroll
    for (int i = 0; i < 4; i++) o[4 + i] = (u16)f2bs(a1[i] * inv);
    return *(uint4*)o;
}

// ---------------- fused gather + layer (both layers via template) --------------------
// Gather kept at native shape: 8 segments/wave, octet-per-segment, 256-thread
// blocks (same 37.5K gather waves as standalone -- round-5 lesson). Means live in
// a [32][72] u16 LDS tile; x-fragments hoisted above the gather.
// L2=0: bf16 plane out (layer 1). L2=1: composite weights, f32+relu out (layer2+head).
template <int L2>
__global__ __launch_bounds__(256) void fused_layer(
    const u16* __restrict__ plane_in, void* __restrict__ outv,
    const int* __restrict__ colidx,
    const int* __restrict__ off_s, const int* __restrict__ off_e,
    const u16* __restrict__ wh, const float* __restrict__ biasC,
    int NA, int NB, int blocksBf) {
    __shared__ __align__(16) u16 mS[32][72];
    const int tid = threadIdx.x;
    const int w = tid >> 6, lane = tid & 63;
    const int oct = lane >> 3, fl = lane & 7;
    const unsigned fo = (unsigned)(fl << 4);
    const char* pA = (const char*)plane_in;
    const char* pB = (const char*)(plane_in + (size_t)NA * 64);
    const int r = lane & 15, q = lane >> 4;
    short8 zf;
#pragma unroll
    for (int j = 0; j < 8; j++) zf[j] = 0;

    if ((int)blockIdx.x < blocksBf) {
        // ================= B path: 32 B-rows =================
        const int row0 = blockIdx.x * 32;
        const int rt = w >> 1;                   // row-tile 0/1
        const int tbase = (w & 1) * 2;           // col-pair
        const int arow = row0 + rt * 16 + r;
        const bool av = arow < NB;
        short8 ax0 = av ? *(const short8*)(pB + (size_t)arow * 128 + q * 16) : zf;
        short8 ax1 = av ? *(const short8*)(pB + (size_t)arow * 128 + 64 + q * 16) : zf;
        {
            int seg = w * 8 + oct;               // 0..31
            int brow = row0 + seg;
            int s0 = 0, s1 = 0;
            if (brow < NB) { s0 = off_s[brow]; s1 = off_e[brow]; }
            uint4 mv = gather_seg(pA, colidx, s0, s1, fo);
            *(uint4*)&mS[seg][fl * 8] = mv;
        }
        __syncthreads();
        const u16* WmT = wh + (size_t)(L2 ? 11 : 0) * 4096;
        const u16* WxT = wh + (size_t)(L2 ? 12 : 6) * 4096;
        const float* bb = biasC + (size_t)(L2 ? 2 : 0) * 64;
        f32x4 acc[2];
#pragma unroll
        for (int t2 = 0; t2 < 2; t2++) {
            float bv = bb[(tbase + t2) * 16 + r];
            acc[t2][0] = bv; acc[t2][1] = bv; acc[t2][2] = bv; acc[t2][3] = bv;
        }
#pragma unroll
        for (int ks = 0; ks < 2; ks++) {
            short8 am = *(const short8*)&mS[rt * 16 + r][ks * 32 + q * 8];
            short8 ax = ks ? ax1 : ax0;
#pragma unroll
            for (int t2 = 0; t2 < 2; t2++) {
                size_t widx = (size_t)((tbase + t2) * 16 + r) * 64 + ks * 32 + q * 8;
                acc[t2] = __builtin_amdgcn_mfma_f32_16x16x32_bf16(am, *(const short8*)(WmT + widx), acc[t2], 0, 0, 0);
                acc[t2] = __builtin_amdgcn_mfma_f32_16x16x32_bf16(ax, *(const short8*)(WxT + widx), acc[t2], 0, 0, 0);
            }
        }
#pragma unroll
        for (int t2 = 0; t2 < 2; t2++) {
            int col = (tbase + t2) * 16 + r;
#pragma unroll
            for (int rr = 0; rr < 4; rr++) {
                int row = row0 + rt * 16 + q * 4 + rr;
                if (row < NB) {
                    float v = acc[t2][rr];
                    if (L2) __builtin_nontemporal_store(fmaxf(v, 0.0f),
                                (float*)outv + (size_t)(NA + row) * 64 + col);
                    else ((u16*)outv)[(size_t)(NA + row) * 64 + col] = (u16)f2bs(v);
                }
            }
        }
    } else {
        // ================= A path: 16 A-rows (32 segments) =================
        const int row0 = ((int)blockIdx.x - blocksBf) * 16;
        const int t = w;                         // col-quarter
        const int arow = row0 + r;
        const bool av = arow < NA;
        short8 ax0 = av ? *(const short8*)(pA + (size_t)arow * 128 + q * 16) : zf;
        short8 ax1 = av ? *(const short8*)(pA + (size_t)arow * 128 + 64 + q * 16) : zf;
        {
            int seg = w * 8 + oct;               // 0..31: <16 -> meanA1, else meanA2
            int rrow = row0 + (seg & 15);
            bool m2 = seg >= 16;
            int s0 = 0, s1 = 0;
            if (rrow < NA) {
                int g = m2 ? (NB + NA + rrow) : (NB + rrow);
                s0 = off_s[g]; s1 = off_e[g];
            }
            uint4 mv = gather_seg(m2 ? pA : pB, colidx, s0, s1, fo);
            *(uint4*)&mS[seg][fl * 8] = mv;
        }
        __syncthreads();
        const u16* Wm1T = wh + (size_t)(L2 ? 13 : 1) * 4096;
        const u16* Wm2T = wh + (size_t)(L2 ? 14 : 2) * 4096;
        const u16* WxT  = wh + (size_t)(L2 ? 15 : 8) * 4096;
        const float* bb = biasC + (size_t)(L2 ? 3 : 1) * 64;
        f32x4 acc;
        {
            float bv = bb[t * 16 + r];
            acc[0] = bv; acc[1] = bv; acc[2] = bv; acc[3] = bv;
        }
#pragma unroll
        for (int ks = 0; ks < 2; ks++) {
            short8 am1 = *(const short8*)&mS[r][ks * 32 + q * 8];
            short8 am2 = *(const short8*)&mS[16 + r][ks * 32 + q * 8];
            short8 ax = ks ? ax1 : ax0;
            size_t widx = (size_t)(t * 16 + r) * 64 + ks * 32 + q * 8;
            acc = __builtin_amdgcn_mfma_f32_16x16x32_bf16(am1, *(const short8*)(Wm1T + widx), acc, 0, 0, 0);
            acc = __builtin_amdgcn_mfma_f32_16x16x32_bf16(am2, *(const short8*)(Wm2T + widx), acc, 0, 0, 0);
            acc = __builtin_amdgcn_mfma_f32_16x16x32_bf16(ax, *(const short8*)(WxT + widx), acc, 0, 0, 0);
        }
        {
            int col = t * 16 + r;
#pragma unroll
            for (int rr = 0; rr < 4; rr++) {
                int row = row0 + q * 4 + rr;
                if (row < NA) {
                    float v = acc[rr];
                    if (L2) __builtin_nontemporal_store(fmaxf(v, 0.0f),
                                (float*)outv + (size_t)row * 64 + col);
                    else ((u16*)outv)[(size_t)row * 64 + col] = (u16)f2bs(v);
                }
            }
        }
    }
}

// ---------------- launch ----------------
extern "C" void kernel_launch(void* const* d_in, const int* in_sizes, int n_in,
                              void* d_out, int out_size, void* d_ws, size_t ws_size,
                              hipStream_t stream) {
    const float* xA_in = (const float*)d_in[0];
    const float* xB_in = (const float*)d_in[1];
    const float* Wn = (const float*)d_in[2];
    const float* Wr = (const float*)d_in[3];
    const float* b = (const float*)d_in[4];
    const float* W_out = (const float*)d_in[5];
    const float* b_out = (const float*)d_in[6];
    const int* src0 = (const int*)d_in[7];
    const int* dst0 = (const int*)d_in[8];
    const int* src1 = (const int*)d_in[9];
    const int* dst1 = (const int*)d_in[10];
    const int* src2 = (const int*)d_in[11];
    const int* dst2 = (const int*)d_in[12];

    const int NA = in_sizes[0] / 64;
    const int NB = in_sizes[1] / 64;
    const int E = in_sizes[7];
    const int M = NB + NA + NA;
    const int total = 3 * E;
    const int K = (M + (1 << BSHIFT) - 1) >> BSHIFT;   // 586 for 300k dst rows

    // ---- workspace ----
    const size_t PL = (size_t)(NA + NB) * 64;
    u16* plane[2];
    plane[0] = (u16*)d_ws;
    plane[1] = plane[0] + PL;
    u16* wh     = plane[1] + PL;                 // 16*4096
    int* gcursor= (int*)(wh + 16 * 4096);        // 1024 (zero-origin counters)
    float* biasC= (float*)(gcursor + 1024);      // 4*64 f32
    int* off_s  = (int*)(biasC + 256);           // M
    int* off_e  = off_s + M;                     // M
    int* colidx = off_e + M;                     // K*CAP
    int* pairs  = colidx + (size_t)K * CAP;      // K*CAP

    // ---- mega launch: partition (first) + convert + weights + composites + bias ----
    int bA = (NA * 16 + 255) / 256, bB = (NB * 16 + 255) / 256;
    int ntiles = (total + PTILE - 1) / PTILE;
    hipMemsetAsync(gcursor, 0, 1024 * 4, stream);
    mega_prep_partition<<<ntiles + bA + bB + 11 + 5 + 1, 256, 0, stream>>>(
        xA_in, xB_in, Wn, Wr, W_out, b, b_out,
        src0, dst0, src1, dst1, src2, dst2,
        plane[0], wh, gcursor, biasC, pairs, NA, NB, E, total, ntiles);

    // ---- per-row CSR within buckets ----
    bucket_fill<<<K, 512, 0, stream>>>(pairs, gcursor, off_s, off_e, colidx, M);

    // ---- fused gather+layer x2 ----
    const int blocksBf = (NB + 31) / 32;
    const int blocksAf = (NA + 15) / 16;
    fused_layer<0><<<blocksBf + blocksAf, 256, 0, stream>>>(
        plane[0], plane[1], colidx, off_s, off_e, wh, biasC, NA, NB, blocksBf);
    fused_layer<1><<<blocksBf + blocksAf, 256, 0, stream>>>(
        plane[1], d_out, colidx, off_s, off_e, wh, biasC, NA, NB, blocksBf);
}

// Round 14
// 358.750 us; speedup vs baseline: 1.1107x; 1.1107x over previous
//
#include <hip/hip_runtime.h>
#include <hip/hip_bf16.h>

typedef __bf16 bf16_t;
typedef unsigned short u16;
typedef short short8 __attribute__((ext_vector_type(8)));
typedef float f32x4 __attribute__((ext_vector_type(4)));

#define BSHIFT 9            // 512 dst-rows per bucket
#define CAP 8192            // fixed slots per bucket (expected 6144 +- 78; 26 sigma)
#define PTILE 8192          // edges per partition tile (1024 thr x 8) -- R12-proven shape

__device__ inline short f2bs(float v) {
    bf16_t h = (bf16_t)v;
    return __builtin_bit_cast(short, h);
}
__device__ inline float uif(unsigned u) { return __builtin_bit_cast(float, u); }

// ---------------- mega kernel: partition (role 0) + prep, 1024 thr, VGPR<=64 ----------
// R13 lesson: merging roles is only free if the merged kernel keeps EVERY role at
// its standalone resource profile. launch_bounds(1024,8) caps VGPR at 64 (2 blocks/CU
// = full 32-wave occupancy); partition tiles keep the proven 8192-edge shape.
// gcursor is ZERO-ORIGIN (gbase = b*CAP + fetch_add) so memset replaces ordered init.
//
// wh mats (transposed [n*64+k], bf16):
//   0..5  Wn[l*3+e]   6,7 WrB[l]   8,9 WrA[l]=Wr[l,1]+Wr[l,2]   10 W_out
//   11 Wn[1,0]@Wout  12 Wr[1,0]@Wout  13 Wn[1,1]@Wout  14 Wn[1,2]@Wout  15 WrA[1]@Wout
// biasC f32[4][64]: 0=b[0,0]; 1=b[0,1]+b[0,2]; 2=b[1,0]@Wout+b_out; 3=(b[1,1]+b[1,2])@Wout+b_out
__global__ __launch_bounds__(1024, 8) void mega_prep_partition(
    const float* __restrict__ xA, const float* __restrict__ xB,
    const float* __restrict__ Wn, const float* __restrict__ Wr,
    const float* __restrict__ Wout, const float* __restrict__ b,
    const float* __restrict__ b_out,
    const int* __restrict__ s0, const int* __restrict__ d0,
    const int* __restrict__ s1, const int* __restrict__ d1,
    const int* __restrict__ s2, const int* __restrict__ d2,
    u16* __restrict__ plane0, u16* __restrict__ wh,
    int* __restrict__ gcursor, float* __restrict__ biasC,
    int* __restrict__ pairs,
    int NA, int NB, int E, int total, int ntiles) {
    __shared__ __align__(16) char smem[32768];   // union: partition 8KB / composite 32KB
    int bi = blockIdx.x;
    int tid = threadIdx.x;

    if (bi < ntiles) {
        // ---- partition role: one 8192-edge tile (R12 shape), scan-free scatter ----
        int* hist = (int*)smem;
        int* gbase = hist + 1024;
        hist[tid] = 0;
        __syncthreads();
        int tile = bi * PTILE;
        int mybkt[8], mypk[8], myrank[8];
#pragma unroll
        for (int j = 0; j < 8; j++) {
            int idx = tile + j * 1024 + tid;
            int g = -1, s = 0;
            if (idx < total) {
                if (idx < E) { s = s0[idx]; g = d0[idx]; }
                else if (idx < 2 * E) { s = s1[idx - E]; g = NB + d1[idx - E]; }
                else { s = s2[idx - 2 * E]; g = NB + NA + d2[idx - 2 * E]; }
            }
            if (g >= 0) {
                mybkt[j] = g >> BSHIFT;
                mypk[j] = ((g & ((1 << BSHIFT) - 1)) << 17) | s;
                myrank[j] = atomicAdd(&hist[mybkt[j]], 1);
            } else mybkt[j] = -1;
        }
        __syncthreads();
        {
            int c = hist[tid];
            if (c) gbase[tid] = tid * CAP + atomicAdd(&gcursor[tid], c);
        }
        __syncthreads();
#pragma unroll
        for (int j = 0; j < 8; j++) {
            if (mybkt[j] >= 0)
                pairs[gbase[mybkt[j]] + myrank[j]] = mypk[j];
        }
        return;
    }

    bi -= ntiles;
    int nA4 = NA * 16, nB4 = NB * 16;
    int bA = (nA4 + 1023) / 1024, bB = (nB4 + 1023) / 1024;
    if (bi < bA + bB) {
        // ---- convert role: f32 -> bf16 plane ----
        const float* in = (bi < bA) ? xA : xB;
        u16* out = (bi < bA) ? plane0 : plane0 + (size_t)NA * 64;
        int i = (bi < bA ? bi : bi - bA) * 1024 + tid;
        int n4 = (bi < bA) ? nA4 : nB4;
        if (i >= n4) return;
        float4 v = ((const float4*)in)[i];
        u16 o[4];
        o[0] = (u16)f2bs(v.x); o[1] = (u16)f2bs(v.y);
        o[2] = (u16)f2bs(v.z); o[3] = (u16)f2bs(v.w);
        *(uint2*)(out + (size_t)i * 4) = *(uint2*)o;
        return;
    }
    if (bi < bA + bB + 11) {
        // ---- weight transpose role ----
        int mat = bi - bA - bB;      // 0..10
        u16* dstp = wh + (size_t)mat * 4096;
        for (int i = tid; i < 4096; i += 1024) {
            int k = i >> 6, n = i & 63;
            float v;
            if (mat < 6) v = Wn[(size_t)mat * 4096 + i];
            else if (mat < 8) v = Wr[(size_t)((mat - 6) * 3 + 0) * 4096 + i];
            else if (mat < 10) v = Wr[(size_t)((mat - 8) * 3 + 1) * 4096 + i]
                                 + Wr[(size_t)((mat - 8) * 3 + 2) * 4096 + i];
            else v = Wout[i];
            dstp[n * 64 + k] = (u16)f2bs(v);
        }
        return;
    }
    if (bi < bA + bB + 11 + 5) {
        // ---- composite role: W' = Wsrc @ W_out, LDS-staged (round-9/10 lesson) ----
        int c = bi - bA - bB - 11;   // 0..4
        const float* Wsrc;
        const float* Wsrc2 = nullptr;
        if (c == 0) Wsrc = Wn + (size_t)3 * 4096;        // Wn[1,0]
        else if (c == 1) Wsrc = Wr + (size_t)3 * 4096;   // Wr[1,0]
        else if (c == 2) Wsrc = Wn + (size_t)4 * 4096;   // Wn[1,1]
        else if (c == 3) Wsrc = Wn + (size_t)5 * 4096;   // Wn[1,2]
        else { Wsrc = Wr + (size_t)4 * 4096; Wsrc2 = Wr + (size_t)5 * 4096; }
        float* Ws = (float*)smem;
        float* Wo = Ws + 4096;
        for (int i = tid; i < 4096; i += 1024) {
            float w = Wsrc[i];
            if (Wsrc2) w += Wsrc2[i];
            Ws[i] = w;
            Wo[i] = Wout[i];
        }
        __syncthreads();
        u16* dstp = wh + (size_t)(11 + c) * 4096;
        for (int it = 0; it < 4; ++it) {
            int i = it * 1024 + tid;
            int k = i >> 6, n = i & 63;
            float p0 = 0.f, p1 = 0.f, p2 = 0.f, p3 = 0.f;
#pragma unroll
            for (int j = 0; j < 64; j += 4) {
                p0 += Ws[k * 64 + j]     * Wo[j * 64 + n];
                p1 += Ws[k * 64 + j + 1] * Wo[(j + 1) * 64 + n];
                p2 += Ws[k * 64 + j + 2] * Wo[(j + 2) * 64 + n];
                p3 += Ws[k * 64 + j + 3] * Wo[(j + 3) * 64 + n];
            }
            dstp[n * 64 + k] = (u16)f2bs((p0 + p1) + (p2 + p3));
        }
        return;
    }
    // ---- bias role ----
    if (tid < 64) {
        int n = tid;
        float s0v = b_out[n], s1v = b_out[n];
        for (int j = 0; j < 64; j++) {
            float wo = Wout[j * 64 + n];
            s0v += b[3 * 64 + j] * wo;                      // b[1,0]
            s1v += (b[4 * 64 + j] + b[5 * 64 + j]) * wo;    // b[1,1]+b[1,2]
        }
        biasC[0 * 64 + n] = b[0 * 64 + n];
        biasC[1 * 64 + n] = b[1 * 64 + n] + b[2 * 64 + n];
        biasC[2 * 64 + n] = s0v;
        biasC[3 * 64 + n] = s1v;
    }
}

// bucket b: order pairs into colidx segments; emit per-row [off_s, off_e).
// Cursor is zero-origin: p1 = b*CAP + gcursor[b].
__global__ __launch_bounds__(512) void bucket_fill(const int* __restrict__ pairs,
                                                   const int* __restrict__ gcursor,
                                                   int* __restrict__ off_s,
                                                   int* __restrict__ off_e,
                                                   int* __restrict__ colidx, int M) {
    int b = blockIdx.x;
    int gb = b << BSHIFT;
    __shared__ int cnt[512], cur[512], wsum[8];
    int tid = threadIdx.x;
    int lane = tid & 63, w = tid >> 6;
    int p0 = b * CAP, p1 = p0 + gcursor[b];
    cnt[tid] = 0;
    __syncthreads();
    for (int e = p0 + tid; e < p1; e += 512)
        atomicAdd(&cnt[(unsigned)pairs[e] >> 17], 1);
    __syncthreads();
    int v = cnt[tid];
    int x = v;
#pragma unroll
    for (int off = 1; off < 64; off <<= 1) {
        int n = __shfl_up(x, off);
        if (lane >= off) x += n;
    }
    if (lane == 63) wsum[w] = x;
    __syncthreads();
    if (tid == 0) {
        int s = 0;
#pragma unroll
        for (int i = 0; i < 8; i++) { int t = wsum[i]; wsum[i] = s; s += t; }
    }
    __syncthreads();
    int excl = x - v + wsum[w];
    cur[tid] = excl;
    int g = gb + tid;
    if (g < M) { off_s[g] = p0 + excl; off_e[g] = p0 + excl + v; }
    __syncthreads();
    for (int e = p0 + tid; e < p1; e += 512) {
        int p = pairs[e];
        int pos = atomicAdd(&cur[(unsigned)p >> 17], 1);
        colidx[p0 + pos] = p & 0x1FFFF;
    }
}

// ---------------- gather one segment -> packed bf16 x8 (per lane, 1/8 row) ----------
// Same quad-pipelined loop as the proven standalone gather (59us, L2-miss-BW bound).
__device__ __forceinline__ void acc8(uint4 u, f32x4& a0, f32x4& a1) {
    a0[0] += uif(u.x << 16); a0[1] += uif(u.x & 0xFFFF0000u);
    a0[2] += uif(u.y << 16); a0[3] += uif(u.y & 0xFFFF0000u);
    a1[0] += uif(u.z << 16); a1[1] += uif(u.z & 0xFFFF0000u);
    a1[2] += uif(u.w << 16); a1[3] += uif(u.w & 0xFFFF0000u);
}

__device__ __forceinline__ uint4 gather_seg(const char* __restrict__ tab,
                                            const int* __restrict__ colidx,
                                            int s0, int s1, unsigned fo) {
    f32x4 a0 = {0.f, 0.f, 0.f, 0.f}, a1 = {0.f, 0.f, 0.f, 0.f};
    int e = s0;
    if (e + 3 < s1) {
        int c0 = colidx[e], c1 = colidx[e + 1];
        int c2 = colidx[e + 2], c3 = colidx[e + 3];
        while (e + 7 < s1) {
            uint4 u0 = *(const uint4*)(tab + (((unsigned)c0 << 7) | fo));
            uint4 u1 = *(const uint4*)(tab + (((unsigned)c1 << 7) | fo));
            uint4 u2 = *(const uint4*)(tab + (((unsigned)c2 << 7) | fo));
            uint4 u3 = *(const uint4*)(tab + (((unsigned)c3 << 7) | fo));
            c0 = colidx[e + 4]; c1 = colidx[e + 5];
            c2 = colidx[e + 6]; c3 = colidx[e + 7];
            acc8(u0, a0, a1); acc8(u1, a0, a1);
            acc8(u2, a0, a1); acc8(u3, a0, a1);
            e += 4;
        }
        {
            uint4 u0 = *(const uint4*)(tab + (((unsigned)c0 << 7) | fo));
            uint4 u1 = *(const uint4*)(tab + (((unsigned)c1 << 7) | fo));
            uint4 u2 = *(const uint4*)(tab + (((unsigned)c2 << 7) | fo));
            uint4 u3 = *(const uint4*)(tab + (((unsigned)c3 << 7) | fo));
            acc8(u0, a0, a1); acc8(u1, a0, a1);
            acc8(u2, a0, a1); acc8(u3, a0, a1);
            e += 4;
        }
    }
    for (; e < s1; ++e) {
        int c = colidx[e];
        uint4 u = *(const uint4*)(tab + (((unsigned)c << 7) | fo));
        acc8(u, a0, a1);
    }
    float inv = 1.0f / fmaxf((float)(s1 - s0), 1.0f);
    u16 o[8];
#pragma unroll
    for (int i = 0; i < 4; i++) o[i] = (u16)f2bs(a0[i] * inv);
#pragma unroll
    for (int i = 0; i < 4; i++) o[4 + i] = (u16)f2bs(a1[i] * inv);
    return *(uint4*)o;
}

// ---------------- fused gather + layer (both layers via template) --------------------
// Gather kept at native shape: 8 segments/wave, octet-per-segment, 256-thread
// blocks (same 37.5K gather waves as standalone -- round-5 lesson). Means live in
// a [32][72] u16 LDS tile; x-fragments hoisted above the gather.
// L2=0: bf16 plane out (layer 1). L2=1: composite weights, f32+relu out (layer2+head).
template <int L2>
__global__ __launch_bounds__(256) void fused_layer(
    const u16* __restrict__ plane_in, void* __restrict__ outv,
    const int* __restrict__ colidx,
    const int* __restrict__ off_s, const int* __restrict__ off_e,
    const u16* __restrict__ wh, const float* __restrict__ biasC,
    int NA, int NB, int blocksBf) {
    __shared__ __align__(16) u16 mS[32][72];
    const int tid = threadIdx.x;
    const int w = tid >> 6, lane = tid & 63;
    const int oct = lane >> 3, fl = lane & 7;
    const unsigned fo = (unsigned)(fl << 4);
    const char* pA = (const char*)plane_in;
    const char* pB = (const char*)(plane_in + (size_t)NA * 64);
    const int r = lane & 15, q = lane >> 4;
    short8 zf;
#pragma unroll
    for (int j = 0; j < 8; j++) zf[j] = 0;

    if ((int)blockIdx.x < blocksBf) {
        // ================= B path: 32 B-rows =================
        const int row0 = blockIdx.x * 32;
        const int rt = w >> 1;                   // row-tile 0/1
        const int tbase = (w & 1) * 2;           // col-pair
        const int arow = row0 + rt * 16 + r;
        const bool av = arow < NB;
        short8 ax0 = av ? *(const short8*)(pB + (size_t)arow * 128 + q * 16) : zf;
        short8 ax1 = av ? *(const short8*)(pB + (size_t)arow * 128 + 64 + q * 16) : zf;
        {
            int seg = w * 8 + oct;               // 0..31
            int brow = row0 + seg;
            int s0 = 0, s1 = 0;
            if (brow < NB) { s0 = off_s[brow]; s1 = off_e[brow]; }
            uint4 mv = gather_seg(pA, colidx, s0, s1, fo);
            *(uint4*)&mS[seg][fl * 8] = mv;
        }
        __syncthreads();
        const u16* WmT = wh + (size_t)(L2 ? 11 : 0) * 4096;
        const u16* WxT = wh + (size_t)(L2 ? 12 : 6) * 4096;
        const float* bb = biasC + (size_t)(L2 ? 2 : 0) * 64;
        f32x4 acc[2];
#pragma unroll
        for (int t2 = 0; t2 < 2; t2++) {
            float bv = bb[(tbase + t2) * 16 + r];
            acc[t2][0] = bv; acc[t2][1] = bv; acc[t2][2] = bv; acc[t2][3] = bv;
        }
#pragma unroll
        for (int ks = 0; ks < 2; ks++) {
            short8 am = *(const short8*)&mS[rt * 16 + r][ks * 32 + q * 8];
            short8 ax = ks ? ax1 : ax0;
#pragma unroll
            for (int t2 = 0; t2 < 2; t2++) {
                size_t widx = (size_t)((tbase + t2) * 16 + r) * 64 + ks * 32 + q * 8;
                acc[t2] = __builtin_amdgcn_mfma_f32_16x16x32_bf16(am, *(const short8*)(WmT + widx), acc[t2], 0, 0, 0);
                acc[t2] = __builtin_amdgcn_mfma_f32_16x16x32_bf16(ax, *(const short8*)(WxT + widx), acc[t2], 0, 0, 0);
            }
        }
#pragma unroll
        for (int t2 = 0; t2 < 2; t2++) {
            int col = (tbase + t2) * 16 + r;
#pragma unroll
            for (int rr = 0; rr < 4; rr++) {
                int row = row0 + rt * 16 + q * 4 + rr;
                if (row < NB) {
                    float v = acc[t2][rr];
                    if (L2) __builtin_nontemporal_store(fmaxf(v, 0.0f),
                                (float*)outv + (size_t)(NA + row) * 64 + col);
                    else ((u16*)outv)[(size_t)(NA + row) * 64 + col] = (u16)f2bs(v);
                }
            }
        }
    } else {
        // ================= A path: 16 A-rows (32 segments) =================
        const int row0 = ((int)blockIdx.x - blocksBf) * 16;
        const int t = w;                         // col-quarter
        const int arow = row0 + r;
        const bool av = arow < NA;
        short8 ax0 = av ? *(const short8*)(pA + (size_t)arow * 128 + q * 16) : zf;
        short8 ax1 = av ? *(const short8*)(pA + (size_t)arow * 128 + 64 + q * 16) : zf;
        {
            int seg = w * 8 + oct;               // 0..31: <16 -> meanA1, else meanA2
            int rrow = row0 + (seg & 15);
            bool m2 = seg >= 16;
            int s0 = 0, s1 = 0;
            if (rrow < NA) {
                int g = m2 ? (NB + NA + rrow) : (NB + rrow);
                s0 = off_s[g]; s1 = off_e[g];
            }
            uint4 mv = gather_seg(m2 ? pA : pB, colidx, s0, s1, fo);
            *(uint4*)&mS[seg][fl * 8] = mv;
        }
        __syncthreads();
        const u16* Wm1T = wh + (size_t)(L2 ? 13 : 1) * 4096;
        const u16* Wm2T = wh + (size_t)(L2 ? 14 : 2) * 4096;
        const u16* WxT  = wh + (size_t)(L2 ? 15 : 8) * 4096;
        const float* bb = biasC + (size_t)(L2 ? 3 : 1) * 64;
        f32x4 acc;
        {
            float bv = bb[t * 16 + r];
            acc[0] = bv; acc[1] = bv; acc[2] = bv; acc[3] = bv;
        }
#pragma unroll
        for (int ks = 0; ks < 2; ks++) {
            short8 am1 = *(const short8*)&mS[r][ks * 32 + q * 8];
            short8 am2 = *(const short8*)&mS[16 + r][ks * 32 + q * 8];
            short8 ax = ks ? ax1 : ax0;
            size_t widx = (size_t)(t * 16 + r) * 64 + ks * 32 + q * 8;
            acc = __builtin_amdgcn_mfma_f32_16x16x32_bf16(am1, *(const short8*)(Wm1T + widx), acc, 0, 0, 0);
            acc = __builtin_amdgcn_mfma_f32_16x16x32_bf16(am2, *(const short8*)(Wm2T + widx), acc, 0, 0, 0);
            acc = __builtin_amdgcn_mfma_f32_16x16x32_bf16(ax, *(const short8*)(WxT + widx), acc, 0, 0, 0);
        }
        {
            int col = t * 16 + r;
#pragma unroll
            for (int rr = 0; rr < 4; rr++) {
                int row = row0 + q * 4 + rr;
                if (row < NA) {
                    float v = acc[rr];
                    if (L2) __builtin_nontemporal_store(fmaxf(v, 0.0f),
                                (float*)outv + (size_t)row * 64 + col);
                    else ((u16*)outv)[(size_t)row * 64 + col] = (u16)f2bs(v);
                }
            }
        }
    }
}

// ---------------- launch ----------------
extern "C" void kernel_launch(void* const* d_in, const int* in_sizes, int n_in,
                              void* d_out, int out_size, void* d_ws, size_t ws_size,
                              hipStream_t stream) {
    const float* xA_in = (const float*)d_in[0];
    const float* xB_in = (const float*)d_in[1];
    const float* Wn = (const float*)d_in[2];
    const float* Wr = (const float*)d_in[3];
    const float* b = (const float*)d_in[4];
    const float* W_out = (const float*)d_in[5];
    const float* b_out = (const float*)d_in[6];
    const int* src0 = (const int*)d_in[7];
    const int* dst0 = (const int*)d_in[8];
    const int* src1 = (const int*)d_in[9];
    const int* dst1 = (const int*)d_in[10];
    const int* src2 = (const int*)d_in[11];
    const int* dst2 = (const int*)d_in[12];

    const int NA = in_sizes[0] / 64;
    const int NB = in_sizes[1] / 64;
    const int E = in_sizes[7];
    const int M = NB + NA + NA;
    const int total = 3 * E;
    const int K = (M + (1 << BSHIFT) - 1) >> BSHIFT;   // 586 for 300k dst rows

    // ---- workspace ----
    const size_t PL = (size_t)(NA + NB) * 64;
    u16* plane[2];
    plane[0] = (u16*)d_ws;
    plane[1] = plane[0] + PL;
    u16* wh     = plane[1] + PL;                 // 16*4096
    int* gcursor= (int*)(wh + 16 * 4096);        // 1024 (zero-origin counters)
    float* biasC= (float*)(gcursor + 1024);      // 4*64 f32
    int* off_s  = (int*)(biasC + 256);           // M
    int* off_e  = off_s + M;                     // M
    int* colidx = off_e + M;                     // K*CAP
    int* pairs  = colidx + (size_t)K * CAP;      // K*CAP

    // ---- mega launch: partition (first, R12 shape) + convert + weights + composites + bias ----
    int bA = (NA * 16 + 1023) / 1024, bB = (NB * 16 + 1023) / 1024;
    int ntiles = (total + PTILE - 1) / PTILE;
    hipMemsetAsync(gcursor, 0, 1024 * 4, stream);
    mega_prep_partition<<<ntiles + bA + bB + 11 + 5 + 1, 1024, 0, stream>>>(
        xA_in, xB_in, Wn, Wr, W_out, b, b_out,
        src0, dst0, src1, dst1, src2, dst2,
        plane[0], wh, gcursor, biasC, pairs, NA, NB, E, total, ntiles);

    // ---- per-row CSR within buckets ----
    bucket_fill<<<K, 512, 0, stream>>>(pairs, gcursor, off_s, off_e, colidx, M);

    // ---- fused gather+layer x2 ----
    const int blocksBf = (NB + 31) / 32;
    const int blocksAf = (NA + 15) / 16;
    fused_layer<0><<<blocksBf + blocksAf, 256, 0, stream>>>(
        plane[0], plane[1], colidx, off_s, off_e, wh, biasC, NA, NB, blocksBf);
    fused_layer<1><<<blocksBf + blocksAf, 256, 0, stream>>>(
        plane[1], d_out, colidx, off_s, off_e, wh, biasC, NA, NB, blocksBf);
}